// Round 1
// baseline (551.543 us; speedup 1.0000x reference)
//
#include <hip/hip_runtime.h>

typedef short s16x8 __attribute__((ext_vector_type(8)));
typedef short s16x4 __attribute__((ext_vector_type(4)));
typedef float f32x4 __attribute__((ext_vector_type(4)));

#define N_ROWS 10000
#define MP 10048   // padded M/K for adj dim (157*64)

__device__ inline short f2bf(float f) {
    unsigned u = __builtin_bit_cast(unsigned, f);
    unsigned r = (u + 0x7fffu + ((u >> 16) & 1u)) >> 16;
    return (short)r;
}

// swizzled LDS index (units: bf16 elements, rows of 64)
__device__ inline int swz(int row, int col) {
    return (row * 64 + col) ^ ((row & 7) << 3);
}

// ---------------------------------------------------------------------------
// Unified MFMA GEMM: C[M x BN] = A[M x K] * B[K x BN]
//  A: row-major, f32 (AF32=1, converted on the fly) or bf16 bits (AF32=0)
//  B: given TRANSPOSED as Bt[BN][ldBt] bf16 bits (row n = column n of B)
//  EPI 0: store C^T bf16 -> Cp[gc*ldC + gm]
//  EPI 1: store relu(C + bias) bf16 row-major -> Cp[gm*ldC + gc]
//  EPI 2: logits = C + bias; row log_softmax; store f32 -> Cp[gm*ldC+gc], gc<40
// ---------------------------------------------------------------------------
template<int BM, int BN, int WM, int WN, int AF32, int EPI>
__global__ __launch_bounds__(512)
void gemm_k(const void* __restrict__ Ap, int ldA, int Mval, int Kval,
            const short* __restrict__ Bt, int ldBt, int Ktiles,
            void* __restrict__ Cp, int ldC, int Cval,
            const float* __restrict__ bias)
{
    constexpr int WTM = BM / WM, WTN = BN / WN;
    constexpr int M_rep = WTM / 16, N_rep = WTN / 16;

    __shared__ alignas(16) short Alds[BM * 64];
    __shared__ alignas(16) short Blds[BN * 64];

    const int tid  = threadIdx.x;
    const int lane = tid & 63;
    const int w    = tid >> 6;
    const int wr   = w / WN, wc = w % WN;
    const int m0   = blockIdx.x * BM;

    f32x4 acc[M_rep][N_rep];
    const f32x4 zero4 = {0.f, 0.f, 0.f, 0.f};
    #pragma unroll
    for (int mi = 0; mi < M_rep; ++mi)
        #pragma unroll
        for (int nj = 0; nj < N_rep; ++nj) acc[mi][nj] = zero4;

    for (int kt = 0; kt < Ktiles; ++kt) {
        const int k0 = kt * 64;
        __syncthreads();
        // ---- stage A (BM x 64) ----
        #pragma unroll
        for (int rep = 0; rep < BM / 64; ++rep) {
            int e   = tid + rep * 512;
            int row = e >> 3, cc = (e & 7) * 8;
            int gm  = m0 + row, gk = k0 + cc;
            s16x8 b;
            if constexpr (AF32) {
                float4 v0 = {0,0,0,0}, v1 = {0,0,0,0};
                if (gm < Mval && gk < Kval) {
                    const float* p = (const float*)Ap + (long)gm * ldA + gk;
                    v0 = *(const float4*)p;
                    v1 = *(const float4*)(p + 4);
                }
                b[0]=f2bf(v0.x); b[1]=f2bf(v0.y); b[2]=f2bf(v0.z); b[3]=f2bf(v0.w);
                b[4]=f2bf(v1.x); b[5]=f2bf(v1.y); b[6]=f2bf(v1.z); b[7]=f2bf(v1.w);
            } else {
                if (gm < Mval && gk < Kval) {
                    b = *(const s16x8*)((const short*)Ap + (long)gm * ldA + gk);
                } else {
                    #pragma unroll
                    for (int j = 0; j < 8; ++j) b[j] = 0;
                }
            }
            *(s16x8*)(&Alds[swz(row, cc)]) = b;
        }
        // ---- stage B (BN x 64) from Bt ----
        #pragma unroll
        for (int rep = 0; rep < BN / 64; ++rep) {
            int e   = tid + rep * 512;
            int row = e >> 3, cc = (e & 7) * 8;
            s16x8 v = *(const s16x8*)(Bt + (long)row * ldBt + k0 + cc);
            *(s16x8*)(&Blds[swz(row, cc)]) = v;
        }
        __syncthreads();
        // ---- compute ----
        #pragma unroll
        for (int kk = 0; kk < 2; ++kk) {
            const int krd = kk * 32 + (lane >> 4) * 8;
            s16x8 af[M_rep], bf[N_rep];
            #pragma unroll
            for (int mi = 0; mi < M_rep; ++mi) {
                int row = wr * WTM + mi * 16 + (lane & 15);
                af[mi] = *(const s16x8*)(&Alds[swz(row, krd)]);
            }
            #pragma unroll
            for (int nj = 0; nj < N_rep; ++nj) {
                int row = wc * WTN + nj * 16 + (lane & 15);
                bf[nj] = *(const s16x8*)(&Blds[swz(row, krd)]);
            }
            #pragma unroll
            for (int mi = 0; mi < M_rep; ++mi)
                #pragma unroll
                for (int nj = 0; nj < N_rep; ++nj)
                    acc[mi][nj] = __builtin_amdgcn_mfma_f32_16x16x32_bf16(
                        af[mi], bf[nj], acc[mi][nj], 0, 0, 0);
        }
    }

    // ---- epilogue ----
    const int mbase = m0 + wr * WTM;
    if constexpr (EPI == 0) {
        short* CT = (short*)Cp;
        #pragma unroll
        for (int mi = 0; mi < M_rep; ++mi) {
            int gm = mbase + mi * 16 + (lane >> 4) * 4;
            if (gm >= Cval) continue;
            #pragma unroll
            for (int nj = 0; nj < N_rep; ++nj) {
                int gc = wc * WTN + nj * 16 + (lane & 15);
                s16x4 p;
                #pragma unroll
                for (int r = 0; r < 4; ++r) p[r] = f2bf(acc[mi][nj][r]);
                *(s16x4*)(CT + (long)gc * ldC + gm) = p;
            }
        }
    } else if constexpr (EPI == 1) {
        short* C = (short*)Cp;
        #pragma unroll
        for (int nj = 0; nj < N_rep; ++nj) {
            int gc = wc * WTN + nj * 16 + (lane & 15);
            float b = bias[gc];
            #pragma unroll
            for (int mi = 0; mi < M_rep; ++mi) {
                int gm = mbase + mi * 16 + (lane >> 4) * 4;
                #pragma unroll
                for (int r = 0; r < 4; ++r) {
                    float v = acc[mi][nj][r] + b;
                    v = fmaxf(v, 0.f);
                    C[(long)(gm + r) * ldC + gc] = f2bf(v);
                }
            }
        }
    } else {
        // EPI == 2: requires WN==1, M_rep==1, N_rep==4 (BN=64 covers all cols)
        float* out = (float*)Cp;
        const int gmb = mbase + (lane >> 4) * 4;
        #pragma unroll
        for (int r = 0; r < 4; ++r) {
            float v[4];
            float mx = -__builtin_inff();
            #pragma unroll
            for (int nj = 0; nj < 4; ++nj) {
                int gc = nj * 16 + (lane & 15);
                float vv = -__builtin_inff();
                if (gc < 40) vv = acc[0][nj][r] + bias[gc];
                v[nj] = vv;
                mx = fmaxf(mx, vv);
            }
            #pragma unroll
            for (int off = 1; off < 16; off <<= 1)
                mx = fmaxf(mx, __shfl_xor(mx, off));
            float s = 0.f;
            #pragma unroll
            for (int nj = 0; nj < 4; ++nj)
                s += (v[nj] == -__builtin_inff()) ? 0.f : __expf(v[nj] - mx);
            #pragma unroll
            for (int off = 1; off < 16; off <<= 1)
                s += __shfl_xor(s, off);
            float lse = mx + __logf(s);
            int gm = gmb + r;
            if (gm < Cval) {
                #pragma unroll
                for (int nj = 0; nj < 4; ++nj) {
                    int gc = nj * 16 + (lane & 15);
                    if (gc < 40) out[(long)gm * ldC + gc] = v[nj] - lse;
                }
            }
        }
    }
}

// W1 [512][256] f32 -> W1t [256][512] bf16
__global__ void transpose_W1(const float* __restrict__ W1, short* __restrict__ W1t) {
    int k = blockIdx.x;      // 0..511
    int c = threadIdx.x;     // 0..255
    W1t[c * 512 + k] = f2bf(W1[k * 256 + c]);
}

// W2 [256][40] f32 -> W2t [64][256] bf16 (zero-padded cols 40..63)
__global__ void transpose_W2(const float* __restrict__ W2, short* __restrict__ W2t) {
    int k = blockIdx.x;      // 0..255
    int c = threadIdx.x;     // 0..63
    float v = (c < 40) ? W2[k * 40 + c] : 0.f;
    W2t[c * 256 + k] = f2bf(v);
}

extern "C" void kernel_launch(void* const* d_in, const int* in_sizes, int n_in,
                              void* d_out, int out_size, void* d_ws, size_t ws_size,
                              hipStream_t stream)
{
    const float* feature = (const float*)d_in[0];  // [10000,512]
    const float* adj     = (const float*)d_in[1];  // [10000,10000]
    const float* W1      = (const float*)d_in[2];  // [512,256]
    const float* b1      = (const float*)d_in[3];  // [256]
    const float* W2      = (const float*)d_in[4];  // [256,40]
    const float* b2      = (const float*)d_in[5];  // [40]
    float* out = (float*)d_out;                    // [10000,40]

    char* w = (char*)d_ws;
    short* XWt = (short*)w;  w += 256L * MP * 2;   // [256][10048] bf16
    short* H   = (short*)w;  w += (long)MP * 256 * 2; // [10048][256] bf16
    short* HWt = (short*)w;  w += 64L * MP * 2;    // [64][10048] bf16
    short* W1t = (short*)w;  w += 256L * 512 * 2;  // [256][512] bf16
    short* W2t = (short*)w;                        // [64][256] bf16

    transpose_W1<<<512, 256, 0, stream>>>(W1, W1t);
    transpose_W2<<<256, 64, 0, stream>>>(W2, W2t);

    // G1: XW = feature @ W1  -> XWt (transposed store)
    gemm_k<64, 256, 2, 4, 1, 0><<<157, 512, 0, stream>>>(
        feature, 512, N_ROWS, 512, W1t, 512, 8, XWt, MP, MP, nullptr);

    // G2: H = relu(adj @ XW + b1) -> H row-major
    gemm_k<64, 256, 2, 4, 1, 1><<<157, 512, 0, stream>>>(
        adj, N_ROWS, N_ROWS, N_ROWS, XWt, MP, 157, H, 256, MP, b1);

    // G3: HW = H @ W2 -> HWt (transposed store)
    gemm_k<128, 64, 8, 1, 0, 0><<<79, 512, 0, stream>>>(
        H, 256, MP, 256, W2t, 256, 4, HWt, MP, MP, nullptr);

    // G4: out = log_softmax(adj @ HW + b2)
    gemm_k<128, 64, 8, 1, 1, 2><<<79, 512, 0, stream>>>(
        adj, N_ROWS, N_ROWS, N_ROWS, HWt, MP, 157, out, 40, N_ROWS, b2);
}

// Round 2
// 296.173 us; speedup vs baseline: 1.8622x; 1.8622x over previous
//
#include <hip/hip_runtime.h>

typedef short s16x8 __attribute__((ext_vector_type(8)));
typedef short s16x4 __attribute__((ext_vector_type(4)));
typedef float f32x4 __attribute__((ext_vector_type(4)));

#define N_ROWS 10000
#define MP 10048   // padded M/K for adj dim (157*64)

__device__ inline short f2bf(float f) {
    unsigned u = __builtin_bit_cast(unsigned, f);
    unsigned r = (u + 0x7fffu + ((u >> 16) & 1u)) >> 16;
    return (short)r;
}

// swizzled LDS index (units: bf16 elements, rows of 64)
__device__ inline int swz(int row, int col) {
    return (row * 64 + col) ^ ((row & 7) << 3);
}

// ---------------------------------------------------------------------------
// Unified MFMA GEMM: C[M x BN] = A[M x K] * B[K x BN]
//  A: row-major, f32 (AF32=1, converted on the fly) or bf16 bits (AF32=0)
//  B: given TRANSPOSED as Bt[BN][ldBt] bf16 bits (row n = column n of B)
//  K-split: blockIdx.y picks tile range [y*ktPerSplit, min(+ktPerSplit,Ktiles))
//  EPI 0: store C^T bf16 -> Cp[gc*ldC + gm]
//  EPI 1: store relu(C + bias) bf16 row-major -> Cp[gm*ldC + gc]
//  EPI 2: logits = C + bias; row log_softmax; store f32 -> Cp[gm*ldC+gc], gc<40
//  EPI 3: store f32 partial -> ((float*)Cp + y*MP*BN)[gm*BN + gc]
// ---------------------------------------------------------------------------
template<int BM, int BN, int WM, int WN, int AF32, int EPI>
__global__ __launch_bounds__(512)
void gemm_k(const void* __restrict__ Ap, int ldA, int Mval, int Kval,
            const short* __restrict__ Bt, int ldBt, int Ktiles,
            void* __restrict__ Cp, int ldC, int Cval,
            const float* __restrict__ bias, int ktPerSplit)
{
    constexpr int WTM = BM / WM, WTN = BN / WN;
    constexpr int M_rep = WTM / 16, N_rep = WTN / 16;

    __shared__ alignas(16) short Alds[BM * 64];
    __shared__ alignas(16) short Blds[BN * 64];

    const int tid  = threadIdx.x;
    const int lane = tid & 63;
    const int w    = tid >> 6;
    const int wr   = w / WN, wc = w % WN;
    const int m0   = blockIdx.x * BM;

    f32x4 acc[M_rep][N_rep];
    const f32x4 zero4 = {0.f, 0.f, 0.f, 0.f};
    #pragma unroll
    for (int mi = 0; mi < M_rep; ++mi)
        #pragma unroll
        for (int nj = 0; nj < N_rep; ++nj) acc[mi][nj] = zero4;

    const int kt0  = blockIdx.y * ktPerSplit;
    int ktEnd = kt0 + ktPerSplit;
    if (ktEnd > Ktiles) ktEnd = Ktiles;

    for (int kt = kt0; kt < ktEnd; ++kt) {
        const int k0 = kt * 64;
        __syncthreads();
        // ---- stage A (BM x 64) ----
        #pragma unroll
        for (int rep = 0; rep < BM / 64; ++rep) {
            int e   = tid + rep * 512;
            int row = e >> 3, cc = (e & 7) * 8;
            int gm  = m0 + row, gk = k0 + cc;
            s16x8 b;
            if constexpr (AF32) {
                float4 v0 = {0,0,0,0}, v1 = {0,0,0,0};
                if (gm < Mval && gk < Kval) {
                    const float* p = (const float*)Ap + (long)gm * ldA + gk;
                    v0 = *(const float4*)p;
                    v1 = *(const float4*)(p + 4);
                }
                b[0]=f2bf(v0.x); b[1]=f2bf(v0.y); b[2]=f2bf(v0.z); b[3]=f2bf(v0.w);
                b[4]=f2bf(v1.x); b[5]=f2bf(v1.y); b[6]=f2bf(v1.z); b[7]=f2bf(v1.w);
            } else {
                if (gm < Mval && gk < Kval) {
                    b = *(const s16x8*)((const short*)Ap + (long)gm * ldA + gk);
                } else {
                    #pragma unroll
                    for (int j = 0; j < 8; ++j) b[j] = 0;
                }
            }
            *(s16x8*)(&Alds[swz(row, cc)]) = b;
        }
        // ---- stage B (BN x 64) from Bt ----
        #pragma unroll
        for (int rep = 0; rep < BN / 64; ++rep) {
            int e   = tid + rep * 512;
            int row = e >> 3, cc = (e & 7) * 8;
            s16x8 v = *(const s16x8*)(Bt + (long)row * ldBt + k0 + cc);
            *(s16x8*)(&Blds[swz(row, cc)]) = v;
        }
        __syncthreads();
        // ---- compute ----
        #pragma unroll
        for (int kk = 0; kk < 2; ++kk) {
            const int krd = kk * 32 + (lane >> 4) * 8;
            s16x8 af[M_rep], bf[N_rep];
            #pragma unroll
            for (int mi = 0; mi < M_rep; ++mi) {
                int row = wr * WTM + mi * 16 + (lane & 15);
                af[mi] = *(const s16x8*)(&Alds[swz(row, krd)]);
            }
            #pragma unroll
            for (int nj = 0; nj < N_rep; ++nj) {
                int row = wc * WTN + nj * 16 + (lane & 15);
                bf[nj] = *(const s16x8*)(&Blds[swz(row, krd)]);
            }
            #pragma unroll
            for (int mi = 0; mi < M_rep; ++mi)
                #pragma unroll
                for (int nj = 0; nj < N_rep; ++nj)
                    acc[mi][nj] = __builtin_amdgcn_mfma_f32_16x16x32_bf16(
                        af[mi], bf[nj], acc[mi][nj], 0, 0, 0);
        }
    }

    // ---- epilogue ----
    const int mbase = m0 + wr * WTM;
    if constexpr (EPI == 0) {
        short* CT = (short*)Cp;
        #pragma unroll
        for (int mi = 0; mi < M_rep; ++mi) {
            int gm = mbase + mi * 16 + (lane >> 4) * 4;
            if (gm >= Cval) continue;
            #pragma unroll
            for (int nj = 0; nj < N_rep; ++nj) {
                int gc = wc * WTN + nj * 16 + (lane & 15);
                s16x4 p;
                #pragma unroll
                for (int r = 0; r < 4; ++r) p[r] = f2bf(acc[mi][nj][r]);
                *(s16x4*)(CT + (long)gc * ldC + gm) = p;
            }
        }
    } else if constexpr (EPI == 1) {
        short* C = (short*)Cp;
        #pragma unroll
        for (int nj = 0; nj < N_rep; ++nj) {
            int gc = wc * WTN + nj * 16 + (lane & 15);
            float b = bias[gc];
            #pragma unroll
            for (int mi = 0; mi < M_rep; ++mi) {
                int gm = mbase + mi * 16 + (lane >> 4) * 4;
                #pragma unroll
                for (int r = 0; r < 4; ++r) {
                    float v = acc[mi][nj][r] + b;
                    v = fmaxf(v, 0.f);
                    C[(long)(gm + r) * ldC + gc] = f2bf(v);
                }
            }
        }
    } else if constexpr (EPI == 2) {
        // requires WN==1, M_rep==1, N_rep==4 (BN=64 covers all cols)
        float* out = (float*)Cp;
        const int gmb = mbase + (lane >> 4) * 4;
        #pragma unroll
        for (int r = 0; r < 4; ++r) {
            float v[4];
            float mx = -__builtin_inff();
            #pragma unroll
            for (int nj = 0; nj < 4; ++nj) {
                int gc = nj * 16 + (lane & 15);
                float vv = -__builtin_inff();
                if (gc < 40) vv = acc[0][nj][r] + bias[gc];
                v[nj] = vv;
                mx = fmaxf(mx, vv);
            }
            #pragma unroll
            for (int off = 1; off < 16; off <<= 1)
                mx = fmaxf(mx, __shfl_xor(mx, off));
            float s = 0.f;
            #pragma unroll
            for (int nj = 0; nj < 4; ++nj)
                s += (v[nj] == -__builtin_inff()) ? 0.f : __expf(v[nj] - mx);
            #pragma unroll
            for (int off = 1; off < 16; off <<= 1)
                s += __shfl_xor(s, off);
            float lse = mx + __logf(s);
            int gm = gmb + r;
            if (gm < Cval) {
                #pragma unroll
                for (int nj = 0; nj < 4; ++nj) {
                    int gc = nj * 16 + (lane & 15);
                    if (gc < 40) out[(long)gm * ldC + gc] = v[nj] - lse;
                }
            }
        }
    } else {
        // EPI == 3: f32 partial store, one buffer per K-split
        float* Cpart = (float*)Cp + (size_t)blockIdx.y * MP * BN;
        #pragma unroll
        for (int nj = 0; nj < N_rep; ++nj) {
            int gc = wc * WTN + nj * 16 + (lane & 15);
            #pragma unroll
            for (int mi = 0; mi < M_rep; ++mi) {
                int gm = mbase + mi * 16 + (lane >> 4) * 4;
                #pragma unroll
                for (int r = 0; r < 4; ++r)
                    Cpart[(long)(gm + r) * BN + gc] = acc[mi][nj][r];
            }
        }
    }
}

// H = relu(sum_s P[s] + b1), bf16 [MP][256]; pad rows -> 0
__global__ __launch_bounds__(256)
void reduce_relu(const float* __restrict__ P, const float* __restrict__ b1,
                 short* __restrict__ H, int KS)
{
    int idx4 = blockIdx.x * 256 + threadIdx.x;   // one f32x4 chunk
    int row  = idx4 >> 6;                        // 64 chunks per 256-wide row
    int col  = (idx4 & 63) * 4;
    s16x4 o;
    if (row < N_ROWS) {
        f32x4 s = {0.f, 0.f, 0.f, 0.f};
        for (int k = 0; k < KS; ++k)
            s += *(const f32x4*)(P + (size_t)k * MP * 256 + (size_t)row * 256 + col);
        #pragma unroll
        for (int j = 0; j < 4; ++j) {
            float v = fmaxf(s[j] + b1[col + j], 0.f);
            o[j] = f2bf(v);
        }
    } else {
        o[0] = o[1] = o[2] = o[3] = 0;
    }
    *(s16x4*)(H + (size_t)row * 256 + col) = o;
}

// out = log_softmax(sum_s P[s] + b2) over 40 cols; P rows are 64 wide
__global__ __launch_bounds__(256)
void reduce_softmax(const float* __restrict__ P, const float* __restrict__ b2,
                    float* __restrict__ out, int KS)
{
    int lane = threadIdx.x & 63;
    int row  = blockIdx.x * 4 + (threadIdx.x >> 6);
    if (row >= N_ROWS) return;
    float v = 0.f;
    for (int k = 0; k < KS; ++k)
        v += P[(size_t)k * MP * 64 + (size_t)row * 64 + lane];
    float vv = (lane < 40) ? v + b2[lane] : -__builtin_inff();
    float mx = vv;
    #pragma unroll
    for (int off = 1; off < 64; off <<= 1)
        mx = fmaxf(mx, __shfl_xor(mx, off));
    float e = (lane < 40) ? __expf(vv - mx) : 0.f;
    float s = e;
    #pragma unroll
    for (int off = 1; off < 64; off <<= 1)
        s += __shfl_xor(s, off);
    float lse = mx + __logf(s);
    if (lane < 40) out[(size_t)row * 40 + lane] = vv - lse;
}

// W1 [512][256] f32 -> W1t [256][512] bf16
__global__ void transpose_W1(const float* __restrict__ W1, short* __restrict__ W1t) {
    int k = blockIdx.x;      // 0..511
    int c = threadIdx.x;     // 0..255
    W1t[c * 512 + k] = f2bf(W1[k * 256 + c]);
}

// W2 [256][40] f32 -> W2t [64][256] bf16 (zero-padded cols 40..63)
__global__ void transpose_W2(const float* __restrict__ W2, short* __restrict__ W2t) {
    int k = blockIdx.x;      // 0..255
    int c = threadIdx.x;     // 0..63
    float v = (c < 40) ? W2[k * 40 + c] : 0.f;
    W2t[c * 256 + k] = f2bf(v);
}

extern "C" void kernel_launch(void* const* d_in, const int* in_sizes, int n_in,
                              void* d_out, int out_size, void* d_ws, size_t ws_size,
                              hipStream_t stream)
{
    const float* feature = (const float*)d_in[0];  // [10000,512]
    const float* adj     = (const float*)d_in[1];  // [10000,10000]
    const float* W1      = (const float*)d_in[2];  // [512,256]
    const float* b1      = (const float*)d_in[3];  // [256]
    const float* W2      = (const float*)d_in[4];  // [256,40]
    const float* b2      = (const float*)d_in[5];  // [40]
    float* out = (float*)d_out;                    // [10000,40]

    char* w = (char*)d_ws;
    short* XWt = (short*)w;  w += 256L * MP * 2;      // [256][10048] bf16
    short* H   = (short*)w;  w += (long)MP * 256 * 2; // [10048][256] bf16
    short* HWt = (short*)w;  w += 64L * MP * 2;       // [64][10048] bf16
    short* W1t = (short*)w;  w += 256L * 512 * 2;     // [256][512] bf16
    short* W2t = (short*)w;  w += 64L * 256 * 2;      // [64][256] bf16
    float* P   = (float*)w;                           // K-split partials (reused G2 then G4)
    size_t baseBytes = (size_t)((char*)P - (char*)d_ws);

    int KS = 1;
    if (ws_size >= baseBytes + 4UL * MP * 256 * 4) KS = 4;
    else if (ws_size >= baseBytes + 2UL * MP * 256 * 4) KS = 2;

    transpose_W1<<<512, 256, 0, stream>>>(W1, W1t);
    transpose_W2<<<256, 64, 0, stream>>>(W2, W2t);

    // G1: XW = feature @ W1 -> XWt (transposed store)
    gemm_k<64, 256, 2, 4, 1, 0><<<157, 512, 0, stream>>>(
        feature, 512, N_ROWS, 512, W1t, 512, 8, XWt, MP, MP, nullptr, 8);

    if (KS > 1) {
        int KTS = (157 + KS - 1) / KS;
        // G2: partial = adj @ XW (K-split)
        gemm_k<64, 256, 2, 4, 1, 3><<<dim3(157, KS), 512, 0, stream>>>(
            adj, N_ROWS, N_ROWS, N_ROWS, XWt, MP, 157, P, 256, MP, nullptr, KTS);
        // R1: H = relu(sum + b1)
        reduce_relu<<<MP * 256 / 4 / 256, 256, 0, stream>>>(P, b1, H, KS);
        // G3: HW = H @ W2 -> HWt
        gemm_k<128, 64, 8, 1, 0, 0><<<79, 512, 0, stream>>>(
            H, 256, MP, 256, W2t, 256, 4, HWt, MP, MP, nullptr, 4);
        // G4: partial = adj @ HW (K-split)
        gemm_k<64, 64, 4, 2, 1, 3><<<dim3(157, KS), 512, 0, stream>>>(
            adj, N_ROWS, N_ROWS, N_ROWS, HWt, MP, 157, P, 64, MP, nullptr, KTS);
        // R2: out = log_softmax(sum + b2)
        reduce_softmax<<<2500, 256, 0, stream>>>(P, b2, out, KS);
    } else {
        // fallback: no split (round-0 behavior)
        gemm_k<64, 256, 2, 4, 1, 1><<<157, 512, 0, stream>>>(
            adj, N_ROWS, N_ROWS, N_ROWS, XWt, MP, 157, H, 256, MP, b1, 157);
        gemm_k<128, 64, 8, 1, 0, 0><<<79, 512, 0, stream>>>(
            H, 256, MP, 256, W2t, 256, 4, HWt, MP, MP, nullptr, 4);
        gemm_k<128, 64, 8, 1, 1, 2><<<79, 512, 0, stream>>>(
            adj, N_ROWS, N_ROWS, N_ROWS, HWt, MP, 157, out, 40, N_ROWS, b2, 157);
    }
}

// Round 3
// 277.967 us; speedup vs baseline: 1.9842x; 1.0655x over previous
//
#include <hip/hip_runtime.h>

typedef short s16x8 __attribute__((ext_vector_type(8)));
typedef short s16x4 __attribute__((ext_vector_type(4)));
typedef float f32x4 __attribute__((ext_vector_type(4)));

#define N_ROWS 10000
#define MP 10048   // padded M/K for adj dim (157*64)

__device__ inline short f2bf(float f) {
    unsigned u = __builtin_bit_cast(unsigned, f);
    unsigned r = (u + 0x7fffu + ((u >> 16) & 1u)) >> 16;
    return (short)r;
}

// swizzled LDS index (units: bf16 elements, rows of 64)
__device__ inline int swz(int row, int col) {
    return (row * 64 + col) ^ ((row & 7) << 3);
}

// ---------------------------------------------------------------------------
// Unified MFMA GEMM with depth-1 register prefetch.
//  C[M x BN] = A[M x K] * B[K x BN]
//  A: row-major, f32 (AF32=1, converted on the fly) or bf16 bits (AF32=0)
//  B: given TRANSPOSED as Bt[BN][ldBt] bf16 bits (row n = column n of B)
//  K-split: blockIdx.y picks tile range [y*ktPerSplit, min(+ktPerSplit,Ktiles))
//  EPI 0: store C^T bf16 -> Cp[gc*ldC + gm]
//  EPI 1: store relu(C + bias) bf16 row-major -> Cp[gm*ldC + gc]
//  EPI 2: logits = C + bias; row log_softmax; store f32 -> Cp[gm*ldC+gc], gc<40
//  EPI 3: store f32 partial -> ((float*)Cp + y*MP*BN)[gm*BN + gc]
// ---------------------------------------------------------------------------
template<int BM, int BN, int WM, int WN, int AF32, int EPI>
__global__ __launch_bounds__(512)
void gemm_k(const void* __restrict__ Ap, int ldA, int Mval, int Kval,
            const short* __restrict__ Bt, int ldBt, int Ktiles,
            void* __restrict__ Cp, int ldC, int Cval,
            const float* __restrict__ bias, int ktPerSplit)
{
    constexpr int WTM = BM / WM, WTN = BN / WN;
    constexpr int M_rep = WTM / 16, N_rep = WTN / 16;
    constexpr int AREP = BM / 64, BREP = BN / 64;

    __shared__ alignas(16) short Alds[BM * 64];
    __shared__ alignas(16) short Blds[BN * 64];

    const int tid  = threadIdx.x;
    const int lane = tid & 63;
    const int w    = tid >> 6;
    const int wr   = w / WN, wc = w % WN;
    const int m0   = blockIdx.x * BM;

    // prefetch registers (statically indexed via unrolled loops)
    float4 va0[AREP], va1[AREP];
    s16x8  vab[AREP];
    s16x8  vb[BREP];

    auto load_regs = [&](int kt) {
        const int k0 = kt * 64;
        #pragma unroll
        for (int rep = 0; rep < AREP; ++rep) {
            int e   = tid + rep * 512;
            int row = e >> 3, cc = (e & 7) * 8;
            int gm  = m0 + row, gk = k0 + cc;
            if constexpr (AF32) {
                float4 z = {0.f, 0.f, 0.f, 0.f};
                va0[rep] = z; va1[rep] = z;
                if (gm < Mval && gk < Kval) {
                    const float* p = (const float*)Ap + (long)gm * ldA + gk;
                    va0[rep] = *(const float4*)p;
                    va1[rep] = *(const float4*)(p + 4);
                }
            } else {
                if (gm < Mval && gk < Kval) {
                    vab[rep] = *(const s16x8*)((const short*)Ap + (long)gm * ldA + gk);
                } else {
                    s16x8 z;
                    #pragma unroll
                    for (int j = 0; j < 8; ++j) z[j] = 0;
                    vab[rep] = z;
                }
            }
        }
        #pragma unroll
        for (int rep = 0; rep < BREP; ++rep) {
            int e   = tid + rep * 512;
            int row = e >> 3, cc = (e & 7) * 8;
            vb[rep] = *(const s16x8*)(Bt + (long)row * ldBt + k0 + cc);
        }
    };

    auto write_lds = [&]() {
        #pragma unroll
        for (int rep = 0; rep < AREP; ++rep) {
            int e   = tid + rep * 512;
            int row = e >> 3, cc = (e & 7) * 8;
            s16x8 b;
            if constexpr (AF32) {
                b[0]=f2bf(va0[rep].x); b[1]=f2bf(va0[rep].y);
                b[2]=f2bf(va0[rep].z); b[3]=f2bf(va0[rep].w);
                b[4]=f2bf(va1[rep].x); b[5]=f2bf(va1[rep].y);
                b[6]=f2bf(va1[rep].z); b[7]=f2bf(va1[rep].w);
            } else {
                b = vab[rep];
            }
            *(s16x8*)(&Alds[swz(row, cc)]) = b;
        }
        #pragma unroll
        for (int rep = 0; rep < BREP; ++rep) {
            int e   = tid + rep * 512;
            int row = e >> 3, cc = (e & 7) * 8;
            *(s16x8*)(&Blds[swz(row, cc)]) = vb[rep];
        }
    };

    f32x4 acc[M_rep][N_rep];
    const f32x4 zero4 = {0.f, 0.f, 0.f, 0.f};
    #pragma unroll
    for (int mi = 0; mi < M_rep; ++mi)
        #pragma unroll
        for (int nj = 0; nj < N_rep; ++nj) acc[mi][nj] = zero4;

    const int kt0 = blockIdx.y * ktPerSplit;
    int ktEnd = kt0 + ktPerSplit;
    if (ktEnd > Ktiles) ktEnd = Ktiles;

    // prologue: stage first tile
    load_regs(kt0);
    write_lds();

    for (int kt = kt0; kt < ktEnd; ++kt) {
        __syncthreads();                       // staged tile visible
        if (kt + 1 < ktEnd) load_regs(kt + 1); // issue next loads (hide under compute)
        // ---- compute tile kt ----
        #pragma unroll
        for (int kk = 0; kk < 2; ++kk) {
            const int krd = kk * 32 + (lane >> 4) * 8;
            s16x8 af[M_rep], bf[N_rep];
            #pragma unroll
            for (int mi = 0; mi < M_rep; ++mi) {
                int row = wr * WTM + mi * 16 + (lane & 15);
                af[mi] = *(const s16x8*)(&Alds[swz(row, krd)]);
            }
            #pragma unroll
            for (int nj = 0; nj < N_rep; ++nj) {
                int row = wc * WTN + nj * 16 + (lane & 15);
                bf[nj] = *(const s16x8*)(&Blds[swz(row, krd)]);
            }
            #pragma unroll
            for (int mi = 0; mi < M_rep; ++mi)
                #pragma unroll
                for (int nj = 0; nj < N_rep; ++nj)
                    acc[mi][nj] = __builtin_amdgcn_mfma_f32_16x16x32_bf16(
                        af[mi], bf[nj], acc[mi][nj], 0, 0, 0);
        }
        __syncthreads();                       // all reads done before overwrite
        if (kt + 1 < ktEnd) write_lds();       // vmcnt wait happens here
    }

    // ---- epilogue ----
    const int mbase = m0 + wr * WTM;
    if constexpr (EPI == 0) {
        short* CT = (short*)Cp;
        #pragma unroll
        for (int mi = 0; mi < M_rep; ++mi) {
            int gm = mbase + mi * 16 + (lane >> 4) * 4;
            if (gm >= Cval) continue;
            #pragma unroll
            for (int nj = 0; nj < N_rep; ++nj) {
                int gc = wc * WTN + nj * 16 + (lane & 15);
                s16x4 p;
                #pragma unroll
                for (int r = 0; r < 4; ++r) p[r] = f2bf(acc[mi][nj][r]);
                *(s16x4*)(CT + (long)gc * ldC + gm) = p;
            }
        }
    } else if constexpr (EPI == 1) {
        short* C = (short*)Cp;
        #pragma unroll
        for (int nj = 0; nj < N_rep; ++nj) {
            int gc = wc * WTN + nj * 16 + (lane & 15);
            float b = bias[gc];
            #pragma unroll
            for (int mi = 0; mi < M_rep; ++mi) {
                int gm = mbase + mi * 16 + (lane >> 4) * 4;
                #pragma unroll
                for (int r = 0; r < 4; ++r) {
                    float v = acc[mi][nj][r] + b;
                    v = fmaxf(v, 0.f);
                    C[(long)(gm + r) * ldC + gc] = f2bf(v);
                }
            }
        }
    } else if constexpr (EPI == 2) {
        // requires WN==1, M_rep==1, N_rep==4 (BN=64 covers all cols)
        float* out = (float*)Cp;
        const int gmb = mbase + (lane >> 4) * 4;
        #pragma unroll
        for (int r = 0; r < 4; ++r) {
            float v[4];
            float mx = -__builtin_inff();
            #pragma unroll
            for (int nj = 0; nj < 4; ++nj) {
                int gc = nj * 16 + (lane & 15);
                float vv = -__builtin_inff();
                if (gc < 40) vv = acc[0][nj][r] + bias[gc];
                v[nj] = vv;
                mx = fmaxf(mx, vv);
            }
            #pragma unroll
            for (int off = 1; off < 16; off <<= 1)
                mx = fmaxf(mx, __shfl_xor(mx, off));
            float s = 0.f;
            #pragma unroll
            for (int nj = 0; nj < 4; ++nj)
                s += (v[nj] == -__builtin_inff()) ? 0.f : __expf(v[nj] - mx);
            #pragma unroll
            for (int off = 1; off < 16; off <<= 1)
                s += __shfl_xor(s, off);
            float lse = mx + __logf(s);
            int gm = gmb + r;
            if (gm < Cval) {
                #pragma unroll
                for (int nj = 0; nj < 4; ++nj) {
                    int gc = nj * 16 + (lane & 15);
                    if (gc < 40) out[(long)gm * ldC + gc] = v[nj] - lse;
                }
            }
        }
    } else {
        // EPI == 3: f32 partial store, one buffer per K-split
        float* Cpart = (float*)Cp + (size_t)blockIdx.y * MP * BN;
        #pragma unroll
        for (int nj = 0; nj < N_rep; ++nj) {
            int gc = wc * WTN + nj * 16 + (lane & 15);
            #pragma unroll
            for (int mi = 0; mi < M_rep; ++mi) {
                int gm = mbase + mi * 16 + (lane >> 4) * 4;
                #pragma unroll
                for (int r = 0; r < 4; ++r)
                    Cpart[(long)(gm + r) * BN + gc] = acc[mi][nj][r];
            }
        }
    }
}

// H = relu(sum_s P[s] + b1), bf16 [MP][256]; pad rows -> 0
__global__ __launch_bounds__(256)
void reduce_relu(const float* __restrict__ P, const float* __restrict__ b1,
                 short* __restrict__ H, int KS)
{
    int idx4 = blockIdx.x * 256 + threadIdx.x;   // one f32x4 chunk
    int row  = idx4 >> 6;                        // 64 chunks per 256-wide row
    int col  = (idx4 & 63) * 4;
    s16x4 o;
    if (row < N_ROWS) {
        f32x4 s = {0.f, 0.f, 0.f, 0.f};
        for (int k = 0; k < KS; ++k)
            s += *(const f32x4*)(P + (size_t)k * MP * 256 + (size_t)row * 256 + col);
        #pragma unroll
        for (int j = 0; j < 4; ++j) {
            float v = fmaxf(s[j] + b1[col + j], 0.f);
            o[j] = f2bf(v);
        }
    } else {
        o[0] = o[1] = o[2] = o[3] = 0;
    }
    *(s16x4*)(H + (size_t)row * 256 + col) = o;
}

// out = log_softmax(sum_s P[s] + b2) over 40 cols; P rows are 64 wide
__global__ __launch_bounds__(256)
void reduce_softmax(const float* __restrict__ P, const float* __restrict__ b2,
                    float* __restrict__ out, int KS)
{
    int lane = threadIdx.x & 63;
    int row  = blockIdx.x * 4 + (threadIdx.x >> 6);
    if (row >= N_ROWS) return;
    float v = 0.f;
    for (int k = 0; k < KS; ++k)
        v += P[(size_t)k * MP * 64 + (size_t)row * 64 + lane];
    float vv = (lane < 40) ? v + b2[lane] : -__builtin_inff();
    float mx = vv;
    #pragma unroll
    for (int off = 1; off < 64; off <<= 1)
        mx = fmaxf(mx, __shfl_xor(mx, off));
    float e = (lane < 40) ? __expf(vv - mx) : 0.f;
    float s = e;
    #pragma unroll
    for (int off = 1; off < 64; off <<= 1)
        s += __shfl_xor(s, off);
    float lse = mx + __logf(s);
    if (lane < 40) out[(size_t)row * 40 + lane] = vv - lse;
}

// W1 [512][256] f32 -> W1t [256][512] bf16
__global__ void transpose_W1(const float* __restrict__ W1, short* __restrict__ W1t) {
    int k = blockIdx.x;      // 0..511
    int c = threadIdx.x;     // 0..255
    W1t[c * 512 + k] = f2bf(W1[k * 256 + c]);
}

// W2 [256][40] f32 -> W2t [64][256] bf16 (zero-padded cols 40..63)
__global__ void transpose_W2(const float* __restrict__ W2, short* __restrict__ W2t) {
    int k = blockIdx.x;      // 0..255
    int c = threadIdx.x;     // 0..63
    float v = (c < 40) ? W2[k * 40 + c] : 0.f;
    W2t[c * 256 + k] = f2bf(v);
}

extern "C" void kernel_launch(void* const* d_in, const int* in_sizes, int n_in,
                              void* d_out, int out_size, void* d_ws, size_t ws_size,
                              hipStream_t stream)
{
    const float* feature = (const float*)d_in[0];  // [10000,512]
    const float* adj     = (const float*)d_in[1];  // [10000,10000]
    const float* W1      = (const float*)d_in[2];  // [512,256]
    const float* b1      = (const float*)d_in[3];  // [256]
    const float* W2      = (const float*)d_in[4];  // [256,40]
    const float* b2      = (const float*)d_in[5];  // [40]
    float* out = (float*)d_out;                    // [10000,40]

    char* w = (char*)d_ws;
    short* XWt = (short*)w;  w += 256L * MP * 2;      // [256][10048] bf16
    short* H   = (short*)w;  w += (long)MP * 256 * 2; // [10048][256] bf16
    short* HWt = (short*)w;  w += 64L * MP * 2;       // [64][10048] bf16
    short* W1t = (short*)w;  w += 256L * 512 * 2;     // [256][512] bf16
    short* W2t = (short*)w;  w += 64L * 256 * 2;      // [64][256] bf16
    float* P   = (float*)w;                           // K-split partials (reused G2 then G4)
    size_t baseBytes = (size_t)((char*)P - (char*)d_ws);

    const size_t pbytes = (size_t)MP * 256 * 4;       // one G2 partial buffer
    int KS = 1;
    if (ws_size >= baseBytes + 8 * pbytes) KS = 8;
    else if (ws_size >= baseBytes + 4 * pbytes) KS = 4;
    else if (ws_size >= baseBytes + 2 * pbytes) KS = 2;

    transpose_W1<<<512, 256, 0, stream>>>(W1, W1t);
    transpose_W2<<<256, 64, 0, stream>>>(W2, W2t);

    // G1: XW = feature @ W1 -> XWt (transposed store)
    gemm_k<64, 256, 2, 4, 1, 0><<<157, 512, 0, stream>>>(
        feature, 512, N_ROWS, 512, W1t, 512, 8, XWt, MP, MP, nullptr, 8);

    if (KS > 1) {
        int KTS = (157 + KS - 1) / KS;
        // G2: partial = adj @ XW (K-split)
        gemm_k<64, 256, 2, 4, 1, 3><<<dim3(157, KS), 512, 0, stream>>>(
            adj, N_ROWS, N_ROWS, N_ROWS, XWt, MP, 157, P, 256, MP, nullptr, KTS);
        // R1: H = relu(sum + b1)
        reduce_relu<<<MP * 256 / 4 / 256, 256, 0, stream>>>(P, b1, H, KS);
        // G3: HW = H @ W2 -> HWt
        gemm_k<64, 64, 4, 2, 0, 0><<<157, 512, 0, stream>>>(
            H, 256, MP, 256, W2t, 256, 4, HWt, MP, MP, nullptr, 4);
        // G4: partial = adj @ HW (K-split)
        gemm_k<64, 64, 4, 2, 1, 3><<<dim3(157, KS), 512, 0, stream>>>(
            adj, N_ROWS, N_ROWS, N_ROWS, HWt, MP, 157, P, 64, MP, nullptr, KTS);
        // R2: out = log_softmax(sum + b2)
        reduce_softmax<<<2500, 256, 0, stream>>>(P, b2, out, KS);
    } else {
        // fallback: no split (round-0 behavior)
        gemm_k<64, 256, 2, 4, 1, 1><<<157, 512, 0, stream>>>(
            adj, N_ROWS, N_ROWS, N_ROWS, XWt, MP, 157, H, 256, MP, b1, 157);
        gemm_k<64, 64, 4, 2, 0, 0><<<157, 512, 0, stream>>>(
            H, 256, MP, 256, W2t, 256, 4, HWt, MP, MP, nullptr, 4);
        gemm_k<128, 64, 8, 1, 1, 2><<<79, 512, 0, stream>>>(
            adj, N_ROWS, N_ROWS, N_ROWS, HWt, MP, 157, out, 40, N_ROWS, b2, 157);
    }
}